// Round 7
// baseline (53.939 us; speedup 1.0000x reference)
//
#include <hip/hip_runtime.h>
#include <math.h>
#include <stdint.h>

#define DIM 4194304
#define N4 (DIM / 4)       // 1048576 float4 per array
#define HALF4 (N4 / 2)     // 524288
#define RBLOCKS 1024
#define RTHREADS 256
#define FBLOCKS 2048       // k_fused: 2048 x 256 threads, 2 float4 (8 elems) per thread
#define FTHREADS 256
#define EPSF 1e-24f
#define SCALE 256.0f

typedef uint32_t u32;
typedef _Float16 h2 __attribute__((ext_vector_type(2)));
typedef __fp16 fp16x2 __attribute__((ext_vector_type(2)));

__device__ __forceinline__ u32 pack2u(float a, float b) {
    fp16x2 r = __builtin_amdgcn_cvt_pkrtz(a, b);
    return __builtin_bit_cast(u32, r);
}
__device__ __forceinline__ u32 dup16(float v) { return pack2u(v, v); }

// --- guaranteed-packed f16 ops (1 instruction each, pure => schedulable) ---
__device__ __forceinline__ u32 pkmul(u32 a, u32 b) {
    u32 r;
    asm("v_pk_mul_f16 %0, %1, %2" : "=v"(r) : "v"(a), "v"(b));
    return r;
}
__device__ __forceinline__ u32 pkfma(u32 a, u32 b, u32 c) {
    asm("v_pk_fma_f16 %0, %1, %2, %0" : "+v"(c) : "v"(a), "v"(b));
    return c;
}
__device__ __forceinline__ u32 pkmax(u32 a, u32 b) {
    u32 r;
    asm("v_pk_max_f16 %0, %1, %2" : "=v"(r) : "v"(a), "v"(b));
    return r;
}
__device__ __forceinline__ float lo16(u32 x) { return (float)__builtin_bit_cast(h2, x).x; }
__device__ __forceinline__ float hi16(u32 x) { return (float)__builtin_bit_cast(h2, x).y; }

// ---------------- Kernel 1: block-partial sums of ||g||^2 and ||xc-xp||^2 ----------------
__global__ __launch_bounds__(RTHREADS) void k_reduce(const float* __restrict__ grad,
                                                     const float* __restrict__ xp,
                                                     const float* __restrict__ xc,
                                                     float* __restrict__ partials) {
    const float4* g4 = reinterpret_cast<const float4*>(grad);
    const float4* p4 = reinterpret_cast<const float4*>(xp);
    const float4* c4 = reinterpret_cast<const float4*>(xc);
    int tid = blockIdx.x * RTHREADS + threadIdx.x;
    float sg = 0.f, sm = 0.f;
    constexpr int STRIDE = RBLOCKS * RTHREADS;
#pragma unroll
    for (int it = 0; it < N4 / STRIDE; ++it) {  // 4 iters
        int i = tid + it * STRIDE;
        float4 gv = g4[i];
        float4 pv = p4[i];
        float4 cv = c4[i];
        sg += gv.x * gv.x + gv.y * gv.y + gv.z * gv.z + gv.w * gv.w;
        float mx = cv.x - pv.x, my = cv.y - pv.y, mz = cv.z - pv.z, mw = cv.w - pv.w;
        sm += mx * mx + my * my + mz * mz + mw * mw;
    }
#pragma unroll
    for (int off = 32; off > 0; off >>= 1) {
        sg += __shfl_down(sg, off);
        sm += __shfl_down(sm, off);
    }
    __shared__ float wg[4], wm[4];
    int wave = threadIdx.x >> 6;
    if ((threadIdx.x & 63) == 0) {
        wg[wave] = sg;
        wm[wave] = sm;
    }
    __syncthreads();
    if (threadIdx.x == 0) {
        partials[2 * blockIdx.x]     = wg[0] + wg[1] + wg[2] + wg[3];
        partials[2 * blockIdx.x + 1] = wm[0] + wm[1] + wm[2] + wm[3];
    }
}

// LDS weight layout (dwords):
// [0] step_eff f32, [1] gs dup16, [2] ms dup16, [3] pad
// [4..33] W21, [36..135] W3, [136..235] W4, [236..335] W5, [336..345] w67
#define L_W21 4
#define L_W3 36
#define L_W4 136
#define L_W5 236
#define L_W67 336

__device__ __forceinline__ void layer10(const u32* Wl, int base, const u32 (&in)[4][10],
                                        u32 (&outp)[4][10], u32 z) {
#pragma unroll
    for (int c = 0; c < 10; ++c) {
        u32 w = Wl[base + c * 10];
        u32 a0 = pkmul(w, in[0][0]);
        u32 a1 = pkmul(w, in[1][0]);
        u32 a2 = pkmul(w, in[2][0]);
        u32 a3 = pkmul(w, in[3][0]);
#pragma unroll
        for (int k = 1; k < 10; ++k) {
            w = Wl[base + c * 10 + k];
            a0 = pkfma(w, in[0][k], a0);
            a1 = pkfma(w, in[1][k], a1);
            a2 = pkfma(w, in[2][k], a2);
            a3 = pkfma(w, in[3][k], a3);
        }
        outp[0][c] = pkmax(a0, z);
        outp[1][c] = pkmax(a1, z);
        outp[2][c] = pkmax(a2, z);
        outp[3][c] = pkmax(a3, z);
    }
}

// -------- Kernel 2: redundant finish + scalar MLP + LDS pack + direction network --------
__global__ __launch_bounds__(FTHREADS) void k_fused(
    const float* __restrict__ grad, const float* __restrict__ xp, const float* __restrict__ xc,
    const float* __restrict__ loss_curr, const float* __restrict__ loss_prev,
    const float* __restrict__ Wc1, const float* __restrict__ Wc2, const float* __restrict__ Wc3,
    const float* __restrict__ Wc4, const float* __restrict__ Wc5, const float* __restrict__ Wc6,
    const float* __restrict__ Wc7, const float* __restrict__ Wl1, const float* __restrict__ Wl2,
    const float* __restrict__ Wl3, const float* __restrict__ Wl4, const float* __restrict__ Wl5,
    const float* __restrict__ partials, float* __restrict__ out) {
    __shared__ u32 Wlds[346];
    __shared__ float red[8];
    const int tid = threadIdx.x;
    const int wave = tid >> 6;

    // ---- phase A (every block, fixed order => identical result): finish reduction ----
    float fg = 0.f, fm = 0.f;
    for (int i = tid; i < RBLOCKS; i += FTHREADS) {  // 4 iters
        fg += partials[2 * i];
        fm += partials[2 * i + 1];
    }
#pragma unroll
    for (int off = 32; off > 0; off >>= 1) {
        fg += __shfl_down(fg, off);
        fm += __shfl_down(fm, off);
    }
    if ((tid & 63) == 0) {
        red[wave] = fg;
        red[4 + wave] = fm;
    }
    __syncthreads();
    if (tid == 0) {
        float g2 = red[0] + red[1] + red[2] + red[3];
        float m2 = red[4] + red[5] + red[6] + red[7];
        float g_norm = sqrtf(g2), m_norm = sqrtf(m2);
        float g_inv = (g_norm > EPSF) ? 1.f / g_norm : 1.f;
        float m_inv = (m_norm > EPSF) ? 1.f / m_norm : 1.f;
        float feats[4] = {log1pf(g_norm), log1pf(m_norm), log1pf(loss_curr[0]),
                          log1pf(loss_prev[0])};
        float h1[8], h2_[8], h3[8], h4[8];
#pragma unroll
        for (int o = 0; o < 8; ++o) {
            float acc = 0.f;
            for (int i = 0; i < 4; ++i) acc += Wl1[o * 4 + i] * feats[i];
            h1[o] = fmaxf(acc, 0.f);
        }
#pragma unroll
        for (int o = 0; o < 8; ++o) {
            float acc = 0.f;
            for (int i = 0; i < 8; ++i) acc += Wl2[o * 8 + i] * h1[i];
            h2_[o] = fmaxf(acc, 0.f);
        }
#pragma unroll
        for (int o = 0; o < 8; ++o) {
            float acc = 0.f;
            for (int i = 0; i < 8; ++i) acc += Wl3[o * 8 + i] * h2_[i];
            h3[o] = fmaxf(acc, 0.f);
        }
#pragma unroll
        for (int o = 0; o < 8; ++o) {
            float acc = 0.f;
            for (int i = 0; i < 8; ++i) acc += Wl4[o * 8 + i] * h3[i];
            h4[o] = acc;  // no relu
        }
        float step = 0.f;
        for (int i = 0; i < 8; ++i) step += Wl5[i] * h4[i];
        Wlds[0] = __builtin_bit_cast(u32, step * (1.f / SCALE));
        Wlds[1] = dup16(g_inv * SCALE);
        Wlds[2] = dup16(m_inv * SCALE);
    }
    // W21 = Wc2 @ Wc1 (10x3); gm column carries 1/SCALE
    if (tid < 30) {
        int o = tid / 3, i = tid % 3;
        float w = 0.f;
        for (int k = 0; k < 10; ++k) w += Wc2[o * 10 + k] * Wc1[k * 3 + i];
        if (i == 2) w *= (1.f / SCALE);
        Wlds[L_W21 + tid] = dup16(w);
    }
    // w67 = Wc7 @ Wc6 (1x10)
    if (tid >= 32 && tid < 42) {
        int j = tid - 32;
        float w = 0.f;
        for (int k = 0; k < 10; ++k) w += Wc7[k] * Wc6[k * 10 + j];
        Wlds[L_W67 + j] = dup16(w);
    }
    // dup-pack W3, W4, W5 (300 entries)
    for (int idx = tid; idx < 300; idx += FTHREADS) {
        int layer = idx / 100, r = idx % 100;
        const float* W = (layer == 0) ? Wc3 : ((layer == 1) ? Wc4 : Wc5);
        Wlds[L_W3 + idx] = dup16(W[r]);
    }
    __syncthreads();

    // ---------------- phase B: direction network, 8 elements/thread ----------------
    const float step_eff = __builtin_bit_cast(float, Wlds[0]);
    const u32 gs = Wlds[1];
    const u32 ms = Wlds[2];
    const u32 z = 0;

    const float4* g4 = reinterpret_cast<const float4*>(grad);
    const float4* p4 = reinterpret_cast<const float4*>(xp);
    const float4* c4 = reinterpret_cast<const float4*>(xc);
    float4* o4 = reinterpret_cast<float4*>(out);

    const int T = blockIdx.x * FTHREADS + tid;
    const int i0 = T, i1 = T + HALF4;

    float4 gv0 = g4[i0], gv1 = g4[i1];
    float4 pv0 = p4[i0], pv1 = p4[i1];
    float4 cv0 = c4[i0], cv1 = c4[i1];

    u32 G[4], M[4], GM[4];
    G[0] = pkmul(gs, pack2u(gv0.x, gv0.y));
    G[1] = pkmul(gs, pack2u(gv0.z, gv0.w));
    G[2] = pkmul(gs, pack2u(gv1.x, gv1.y));
    G[3] = pkmul(gs, pack2u(gv1.z, gv1.w));
    M[0] = pkmul(ms, pack2u(cv0.x - pv0.x, cv0.y - pv0.y));
    M[1] = pkmul(ms, pack2u(cv0.z - pv0.z, cv0.w - pv0.w));
    M[2] = pkmul(ms, pack2u(cv1.x - pv1.x, cv1.y - pv1.y));
    M[3] = pkmul(ms, pack2u(cv1.z - pv1.z, cv1.w - pv1.w));
#pragma unroll
    for (int p = 0; p < 4; ++p) GM[p] = pkmul(G[p], M[p]);

    u32 ta[4][10], tb[4][10];
    // layer A: relu(W21 @ [g, m, g*m])
#pragma unroll
    for (int c = 0; c < 10; ++c) {
        u32 w0 = Wlds[L_W21 + c * 3];
        u32 w1 = Wlds[L_W21 + c * 3 + 1];
        u32 w2 = Wlds[L_W21 + c * 3 + 2];
#pragma unroll
        for (int p = 0; p < 4; ++p) {
            u32 acc = pkmul(w2, GM[p]);
            acc = pkfma(w1, M[p], acc);
            acc = pkfma(w0, G[p], acc);
            ta[p][c] = pkmax(acc, z);
        }
    }
    layer10(Wlds, L_W3, ta, tb, z);
    layer10(Wlds, L_W4, tb, ta, z);
    layer10(Wlds, L_W5, ta, tb, z);

    // final: dir = w67 . u
    u32 d[4];
    {
        u32 w = Wlds[L_W67];
#pragma unroll
        for (int p = 0; p < 4; ++p) d[p] = pkmul(w, tb[p][0]);
#pragma unroll
        for (int k = 1; k < 10; ++k) {
            w = Wlds[L_W67 + k];
#pragma unroll
            for (int p = 0; p < 4; ++p) d[p] = pkfma(w, tb[p][k], d[p]);
        }
    }

    float4 ov0, ov1;
    ov0.x = fmaf(-step_eff, lo16(d[0]), cv0.x);
    ov0.y = fmaf(-step_eff, hi16(d[0]), cv0.y);
    ov0.z = fmaf(-step_eff, lo16(d[1]), cv0.z);
    ov0.w = fmaf(-step_eff, hi16(d[1]), cv0.w);
    ov1.x = fmaf(-step_eff, lo16(d[2]), cv1.x);
    ov1.y = fmaf(-step_eff, hi16(d[2]), cv1.y);
    ov1.z = fmaf(-step_eff, lo16(d[3]), cv1.z);
    ov1.w = fmaf(-step_eff, hi16(d[3]), cv1.w);
    o4[i0] = ov0;
    o4[i1] = ov1;
}

extern "C" void kernel_launch(void* const* d_in, const int* in_sizes, int n_in,
                              void* d_out, int out_size, void* d_ws, size_t ws_size,
                              hipStream_t stream) {
    const float* grad      = (const float*)d_in[0];
    const float* xp        = (const float*)d_in[1];
    const float* xc        = (const float*)d_in[2];
    const float* loss_curr = (const float*)d_in[3];
    const float* loss_prev = (const float*)d_in[4];
    const float* Wc1 = (const float*)d_in[5];
    const float* Wc2 = (const float*)d_in[6];
    const float* Wc3 = (const float*)d_in[7];
    const float* Wc4 = (const float*)d_in[8];
    const float* Wc5 = (const float*)d_in[9];
    const float* Wc6 = (const float*)d_in[10];
    const float* Wc7 = (const float*)d_in[11];
    const float* Wl1 = (const float*)d_in[12];
    const float* Wl2 = (const float*)d_in[13];
    const float* Wl3 = (const float*)d_in[14];
    const float* Wl4 = (const float*)d_in[15];
    const float* Wl5 = (const float*)d_in[16];

    float* partials = (float*)d_ws;  // 2 * RBLOCKS floats
    float* out      = (float*)d_out;

    k_reduce<<<RBLOCKS, RTHREADS, 0, stream>>>(grad, xp, xc, partials);
    k_fused<<<FBLOCKS, FTHREADS, 0, stream>>>(grad, xp, xc, loss_curr, loss_prev, Wc1, Wc2,
                                              Wc3, Wc4, Wc5, Wc6, Wc7, Wl1, Wl2, Wl3, Wl4,
                                              Wl5, partials, out);
}

// Round 9
// 53.104 us; speedup vs baseline: 1.0157x; 1.0157x over previous
//
#include <hip/hip_runtime.h>
#include <math.h>
#include <stdint.h>

#define DIM 4194304
#define RBLOCKS 1024
#define RTHREADS 256
#define FBLOCKS 2048
#define FTHREADS 256
#define TOTTH (FBLOCKS * FTHREADS)  // 524288
#define PASSES (DIM / TOTTH)        // 8
#define EPSF 1e-24f
#define SCALE 256.0f

// d_ws dword layout
#define WS_PART 0     // 2048: per-block partial sums
#define WS_W21 2048   // 128 dwords: layer-A A-frag lower K-half (per-lane 2 dwords)
#define WS_W3 2176
#define WS_W4 2304
#define WS_W5 2432
#define WS_W67 2560   // 16 f32 (w67 padded)

typedef uint32_t u32;
typedef __fp16 fp16x2 __attribute__((ext_vector_type(2)));
typedef __fp16 half8 __attribute__((ext_vector_type(8)));
typedef float f32x4 __attribute__((ext_vector_type(4)));
typedef uint32_t u32x2 __attribute__((ext_vector_type(2)));
typedef uint32_t u32x4 __attribute__((ext_vector_type(4)));

__device__ __forceinline__ u32 pack2u(float a, float b) {
    fp16x2 r = __builtin_amdgcn_cvt_pkrtz(a, b);
    return __builtin_bit_cast(u32, r);
}

// gfx950-native MFMA (HW-verified shape): D = A(16x32) * B(32x16) + C
__device__ __forceinline__ f32x4 mfma32(half8 a, half8 b, f32x4 c) {
    return __builtin_amdgcn_mfma_f32_16x16x32_f16(a, b, c, 0, 0, 0);
}
// relu(f32x4) -> lower-K-half B-fragment (halves 0..3 = values, 4..7 = 0)
__device__ __forceinline__ half8 relucvt8(f32x4 a) {
    u32 lo0 = pack2u(fmaxf(a[0], 0.f), fmaxf(a[1], 0.f));
    u32 lo1 = pack2u(fmaxf(a[2], 0.f), fmaxf(a[3], 0.f));
    u32x4 r = {lo0, lo1, 0u, 0u};
    return __builtin_bit_cast(half8, r);
}

// ------- Kernel 1: block-partial norms; block 0 also packs MFMA weight fragments -------
__global__ __launch_bounds__(RTHREADS) void k_reduce(
    const float* __restrict__ grad, const float* __restrict__ xp, const float* __restrict__ xc,
    const float* __restrict__ Wc1, const float* __restrict__ Wc2, const float* __restrict__ Wc3,
    const float* __restrict__ Wc4, const float* __restrict__ Wc5, const float* __restrict__ Wc6,
    const float* __restrict__ Wc7, float* __restrict__ ws) {
    if (blockIdx.x == 0) {
        u32* wsu = (u32*)ws;
        int t = threadIdx.x;
        if (t < 128) {
            // dword t = lane*2 + d holds W[m][k0], W[m][k0+1]; m=lane&15, g=lane>>4, k0=4g+2d
            int lane = t >> 1, d = t & 1;
            int m = lane & 15, gg = lane >> 4;
            int k0 = 4 * gg + 2 * d;
            // layer A: W21 = Wc2 @ Wc1 (10x3), gm column (k==2) carries 1/SCALE
            float a0 = 0.f, a1 = 0.f;
            if (m < 10 && k0 < 3) {
                for (int j = 0; j < 10; ++j) a0 += Wc2[m * 10 + j] * Wc1[j * 3 + k0];
                if (k0 == 2) a0 *= (1.f / SCALE);
            }
            if (m < 10 && k0 + 1 < 3) {
                for (int j = 0; j < 10; ++j) a1 += Wc2[m * 10 + j] * Wc1[j * 3 + k0 + 1];
                if (k0 + 1 == 2) a1 *= (1.f / SCALE);
            }
            wsu[WS_W21 + t] = pack2u(a0, a1);
            float v0, v1;
            v0 = (m < 10 && k0 < 10) ? Wc3[m * 10 + k0] : 0.f;
            v1 = (m < 10 && k0 + 1 < 10) ? Wc3[m * 10 + k0 + 1] : 0.f;
            wsu[WS_W3 + t] = pack2u(v0, v1);
            v0 = (m < 10 && k0 < 10) ? Wc4[m * 10 + k0] : 0.f;
            v1 = (m < 10 && k0 + 1 < 10) ? Wc4[m * 10 + k0 + 1] : 0.f;
            wsu[WS_W4 + t] = pack2u(v0, v1);
            v0 = (m < 10 && k0 < 10) ? Wc5[m * 10 + k0] : 0.f;
            v1 = (m < 10 && k0 + 1 < 10) ? Wc5[m * 10 + k0 + 1] : 0.f;
            wsu[WS_W5 + t] = pack2u(v0, v1);
        }
        if (t >= 128 && t < 144) {
            int j = t - 128;
            float w = 0.f;
            if (j < 10)
                for (int k = 0; k < 10; ++k) w += Wc7[k] * Wc6[k * 10 + j];
            ws[WS_W67 + j] = w;
        }
    }
    const float4* g4 = reinterpret_cast<const float4*>(grad);
    const float4* p4 = reinterpret_cast<const float4*>(xp);
    const float4* c4 = reinterpret_cast<const float4*>(xc);
    int tid = blockIdx.x * RTHREADS + threadIdx.x;
    float sg = 0.f, sm = 0.f;
    constexpr int STRIDE = RBLOCKS * RTHREADS;
#pragma unroll
    for (int it = 0; it < (DIM / 4) / STRIDE; ++it) {  // 4 iters
        int i = tid + it * STRIDE;
        float4 gv = g4[i];
        float4 pv = p4[i];
        float4 cv = c4[i];
        sg += gv.x * gv.x + gv.y * gv.y + gv.z * gv.z + gv.w * gv.w;
        float mx = cv.x - pv.x, my = cv.y - pv.y, mz = cv.z - pv.z, mw = cv.w - pv.w;
        sm += mx * mx + my * my + mz * mz + mw * mw;
    }
#pragma unroll
    for (int off = 32; off > 0; off >>= 1) {
        sg += __shfl_down(sg, off);
        sm += __shfl_down(sm, off);
    }
    __shared__ float wg[4], wm[4];
    int wave = threadIdx.x >> 6;
    if ((threadIdx.x & 63) == 0) {
        wg[wave] = sg;
        wm[wave] = sm;
    }
    __syncthreads();
    if (threadIdx.x == 0) {
        ws[WS_PART + 2 * blockIdx.x]     = wg[0] + wg[1] + wg[2] + wg[3];
        ws[WS_PART + 2 * blockIdx.x + 1] = wm[0] + wm[1] + wm[2] + wm[3];
    }
}

// ------- Kernel 2: redundant scalar finish + MFMA-chained direction network -------
__global__ __launch_bounds__(FTHREADS) void k_fused(
    const float* __restrict__ grad, const float* __restrict__ xp, const float* __restrict__ xc,
    const float* __restrict__ loss_curr, const float* __restrict__ loss_prev,
    const float* __restrict__ Wl1, const float* __restrict__ Wl2, const float* __restrict__ Wl3,
    const float* __restrict__ Wl4, const float* __restrict__ Wl5,
    const float* __restrict__ ws, float* __restrict__ out) {
    __shared__ float sc[3];
    __shared__ float red[8];
    const int tid = threadIdx.x;

    // ---- phase A: every block finishes the norms in fixed order (identical result) ----
    {
        float fg = 0.f, fm = 0.f;
        for (int i = tid; i < RBLOCKS; i += FTHREADS) {
            fg += ws[WS_PART + 2 * i];
            fm += ws[WS_PART + 2 * i + 1];
        }
#pragma unroll
        for (int off = 32; off > 0; off >>= 1) {
            fg += __shfl_down(fg, off);
            fm += __shfl_down(fm, off);
        }
        int wv = tid >> 6;
        if ((tid & 63) == 0) {
            red[wv] = fg;
            red[4 + wv] = fm;
        }
        __syncthreads();
        if (tid == 0) {
            float g2 = red[0] + red[1] + red[2] + red[3];
            float m2 = red[4] + red[5] + red[6] + red[7];
            float g_norm = sqrtf(g2), m_norm = sqrtf(m2);
            float g_inv = (g_norm > EPSF) ? 1.f / g_norm : 1.f;
            float m_inv = (m_norm > EPSF) ? 1.f / m_norm : 1.f;
            float feats[4] = {log1pf(g_norm), log1pf(m_norm), log1pf(loss_curr[0]),
                              log1pf(loss_prev[0])};
            float h1[8], h2_[8], h3[8], h4[8];
#pragma unroll
            for (int o = 0; o < 8; ++o) {
                float acc = 0.f;
                for (int i = 0; i < 4; ++i) acc += Wl1[o * 4 + i] * feats[i];
                h1[o] = fmaxf(acc, 0.f);
            }
#pragma unroll
            for (int o = 0; o < 8; ++o) {
                float acc = 0.f;
                for (int i = 0; i < 8; ++i) acc += Wl2[o * 8 + i] * h1[i];
                h2_[o] = fmaxf(acc, 0.f);
            }
#pragma unroll
            for (int o = 0; o < 8; ++o) {
                float acc = 0.f;
                for (int i = 0; i < 8; ++i) acc += Wl3[o * 8 + i] * h2_[i];
                h3[o] = fmaxf(acc, 0.f);
            }
#pragma unroll
            for (int o = 0; o < 8; ++o) {
                float acc = 0.f;
                for (int i = 0; i < 8; ++i) acc += Wl4[o * 8 + i] * h3[i];
                h4[o] = acc;  // no relu
            }
            float step = 0.f;
            for (int i = 0; i < 8; ++i) step += Wl5[i] * h4[i];
            sc[0] = g_inv * SCALE;
            sc[1] = m_inv * SCALE;
            sc[2] = step * (1.f / SCALE);
        }
        __syncthreads();
    }
    const float gs = sc[0], ms = sc[1], step_eff = sc[2];

    // ---- per-lane weight fragments: lower K-half from ws, upper K-half = 0 ----
    const u32* wsu = (const u32*)ws;
    const int lane = tid & 63;
    const int n = lane & 15, g = lane >> 4;
#define LOADFRAG(NAME, OFS)                                                    \
    half8 NAME;                                                                \
    {                                                                          \
        u32x2 lo = ((const u32x2*)(wsu + (OFS)))[lane];                        \
        u32x4 fr = {lo[0], lo[1], 0u, 0u};                                     \
        NAME = __builtin_bit_cast(half8, fr);                                  \
    }
    LOADFRAG(w21f, WS_W21)
    LOADFRAG(w3f, WS_W3)
    LOADFRAG(w4f, WS_W4)
    LOADFRAG(w5f, WS_W5)
#undef LOADFRAG
    half8 w67f;
    {
        const float* w67p = ws + WS_W67;  // w67 replicated into all 16 A-rows
        u32x4 fr = {pack2u(w67p[4 * g], w67p[4 * g + 1]),
                    pack2u(w67p[4 * g + 2], w67p[4 * g + 3]), 0u, 0u};
        w67f = __builtin_bit_cast(half8, fr);
    }
    const int idx0 = n << 2, idx1 = (n + 16) << 2, idx2 = (n + 32) << 2, idx3 = (n + 48) << 2;
    const f32x4 zf = {0.f, 0.f, 0.f, 0.f};

    int ebase = (blockIdx.x * (FTHREADS / 64) + (tid >> 6)) * 64 + lane;
    int e = ebase;
    float gvv = grad[e], pvv = xp[e], cvv = xc[e];
#pragma unroll
    for (int p = 0; p < PASSES; ++p) {
        int en = (p + 1 < PASSES) ? (e + TOTTH) : 0;  // prefetch next pass (clamped)
        float gvn = grad[en], pvn = xp[en], cvn = xc[en];

        float Gf = gvv * gs;
        float Mf = (cvv - pvv) * ms;
        float GMf = Gf * Mf;
        u32 pk0 = pack2u(Gf, Mf), pk1 = pack2u(GMf, 0.f);

        float d0, d1, d2, d3;
#define TILE(IDX, DOUT)                                                       \
    {                                                                         \
        u32 b0 = (u32)__builtin_amdgcn_ds_bpermute(IDX, (int)pk0);            \
        u32 b1 = (u32)__builtin_amdgcn_ds_bpermute(IDX, (int)pk1);            \
        u32x4 bb = {b0, b1, 0u, 0u};                                          \
        half8 B = __builtin_bit_cast(half8, bb);                              \
        f32x4 acc = mfma32(w21f, B, zf);                                      \
        acc = mfma32(w3f, relucvt8(acc), zf);                                 \
        acc = mfma32(w4f, relucvt8(acc), zf);                                 \
        acc = mfma32(w5f, relucvt8(acc), zf);                                 \
        acc = mfma32(w67f, relucvt8(acc), zf);                                \
        DOUT = acc[0];                                                        \
    }
        TILE(idx0, d0)
        TILE(idx1, d1)
        TILE(idx2, d2)
        TILE(idx3, d3)
#undef TILE
        float dsel = (g == 0) ? d0 : (g == 1) ? d1 : (g == 2) ? d2 : d3;
        out[e] = fmaf(-step_eff, dsel, cvv);

        e = (p + 1 < PASSES) ? en : e;
        gvv = gvn;
        pvv = pvn;
        cvv = cvn;
    }
}

extern "C" void kernel_launch(void* const* d_in, const int* in_sizes, int n_in,
                              void* d_out, int out_size, void* d_ws, size_t ws_size,
                              hipStream_t stream) {
    const float* grad      = (const float*)d_in[0];
    const float* xp        = (const float*)d_in[1];
    const float* xc        = (const float*)d_in[2];
    const float* loss_curr = (const float*)d_in[3];
    const float* loss_prev = (const float*)d_in[4];
    const float* Wc1 = (const float*)d_in[5];
    const float* Wc2 = (const float*)d_in[6];
    const float* Wc3 = (const float*)d_in[7];
    const float* Wc4 = (const float*)d_in[8];
    const float* Wc5 = (const float*)d_in[9];
    const float* Wc6 = (const float*)d_in[10];
    const float* Wc7 = (const float*)d_in[11];
    const float* Wl1 = (const float*)d_in[12];
    const float* Wl2 = (const float*)d_in[13];
    const float* Wl3 = (const float*)d_in[14];
    const float* Wl4 = (const float*)d_in[15];
    const float* Wl5 = (const float*)d_in[16];

    float* ws  = (float*)d_ws;
    float* out = (float*)d_out;

    k_reduce<<<RBLOCKS, RTHREADS, 0, stream>>>(grad, xp, xc, Wc1, Wc2, Wc3, Wc4, Wc5, Wc6,
                                               Wc7, ws);
    k_fused<<<FBLOCKS, FTHREADS, 0, stream>>>(grad, xp, xc, loss_curr, loss_prev, Wl1, Wl2,
                                              Wl3, Wl4, Wl5, ws, out);
}

// Round 10
// 39.974 us; speedup vs baseline: 1.3494x; 1.3285x over previous
//
#include <hip/hip_runtime.h>
#include <math.h>
#include <stdint.h>

#define DIM 4194304
#define RBLOCKS 1024
#define RTHREADS 256
#define FBLOCKS 2048
#define FTHREADS 256
#define TOTTH (FBLOCKS * FTHREADS)  // 524288
#define PASSES (DIM / TOTTH)        // 8
#define EPSF 1e-24f
#define SCALE 256.0f

// d_ws dword layout
#define WS_PART 0     // 2048: per-block partial sums
#define WS_W21 2048   // 128 dwords: layer-A A-frag lower K-half (per-lane 2 dwords)
#define WS_W3 2176
#define WS_W4 2304
#define WS_W5 2432
#define WS_W67 2560   // 16 f32 (w67 padded)

typedef uint32_t u32;
typedef __fp16 fp16x2 __attribute__((ext_vector_type(2)));
typedef __fp16 half8 __attribute__((ext_vector_type(8)));
typedef float f32x4 __attribute__((ext_vector_type(4)));
typedef uint32_t u32x2 __attribute__((ext_vector_type(2)));
typedef uint32_t u32x4 __attribute__((ext_vector_type(4)));

__device__ __forceinline__ u32 pack2u(float a, float b) {
    fp16x2 r = __builtin_amdgcn_cvt_pkrtz(a, b);
    return __builtin_bit_cast(u32, r);
}

// gfx950-native MFMA (HW-verified shape): D = A(16x32) * B(32x16) + C
__device__ __forceinline__ f32x4 mfma32(half8 a, half8 b, f32x4 c) {
    return __builtin_amdgcn_mfma_f32_16x16x32_f16(a, b, c, 0, 0, 0);
}
// relu(f32x4) -> lower-K-half B-fragment: cvt_pkrtz x2 then packed max x2 (4 VALU)
__device__ __forceinline__ half8 relucvt8(f32x4 a) {
    fp16x2 z2 = {(__fp16)0.f, (__fp16)0.f};
    fp16x2 c0 = __builtin_amdgcn_cvt_pkrtz(a[0], a[1]);
    fp16x2 c1 = __builtin_amdgcn_cvt_pkrtz(a[2], a[3]);
    c0 = __builtin_elementwise_max(c0, z2);
    c1 = __builtin_elementwise_max(c1, z2);
    u32x4 r = {__builtin_bit_cast(u32, c0), __builtin_bit_cast(u32, c1), 0u, 0u};
    return __builtin_bit_cast(half8, r);
}

// ------- Kernel 1: block-partial norms; block 0 also packs MFMA weight fragments -------
__global__ __launch_bounds__(RTHREADS) void k_reduce(
    const float* __restrict__ grad, const float* __restrict__ xp, const float* __restrict__ xc,
    const float* __restrict__ Wc1, const float* __restrict__ Wc2, const float* __restrict__ Wc3,
    const float* __restrict__ Wc4, const float* __restrict__ Wc5, const float* __restrict__ Wc6,
    const float* __restrict__ Wc7, float* __restrict__ ws) {
    if (blockIdx.x == 0) {
        u32* wsu = (u32*)ws;
        int t = threadIdx.x;
        if (t < 128) {
            // dword t = lane*2 + d holds W[m][k0], W[m][k0+1]; m=lane&15, g=lane>>4, k0=4g+2d
            int lane = t >> 1, d = t & 1;
            int m = lane & 15, gg = lane >> 4;
            int k0 = 4 * gg + 2 * d;
            // layer A: W21 = Wc2 @ Wc1 (10x3), gm column (k==2) carries 1/SCALE
            float a0 = 0.f, a1 = 0.f;
            if (m < 10 && k0 < 3) {
                for (int j = 0; j < 10; ++j) a0 += Wc2[m * 10 + j] * Wc1[j * 3 + k0];
                if (k0 == 2) a0 *= (1.f / SCALE);
            }
            if (m < 10 && k0 + 1 < 3) {
                for (int j = 0; j < 10; ++j) a1 += Wc2[m * 10 + j] * Wc1[j * 3 + k0 + 1];
                if (k0 + 1 == 2) a1 *= (1.f / SCALE);
            }
            wsu[WS_W21 + t] = pack2u(a0, a1);
            float v0, v1;
            v0 = (m < 10 && k0 < 10) ? Wc3[m * 10 + k0] : 0.f;
            v1 = (m < 10 && k0 + 1 < 10) ? Wc3[m * 10 + k0 + 1] : 0.f;
            wsu[WS_W3 + t] = pack2u(v0, v1);
            v0 = (m < 10 && k0 < 10) ? Wc4[m * 10 + k0] : 0.f;
            v1 = (m < 10 && k0 + 1 < 10) ? Wc4[m * 10 + k0 + 1] : 0.f;
            wsu[WS_W4 + t] = pack2u(v0, v1);
            v0 = (m < 10 && k0 < 10) ? Wc5[m * 10 + k0] : 0.f;
            v1 = (m < 10 && k0 + 1 < 10) ? Wc5[m * 10 + k0 + 1] : 0.f;
            wsu[WS_W5 + t] = pack2u(v0, v1);
        }
        if (t >= 128 && t < 144) {
            int j = t - 128;
            float w = 0.f;
            if (j < 10)
                for (int k = 0; k < 10; ++k) w += Wc7[k] * Wc6[k * 10 + j];
            ws[WS_W67 + j] = w;
        }
    }
    const float4* g4 = reinterpret_cast<const float4*>(grad);
    const float4* p4 = reinterpret_cast<const float4*>(xp);
    const float4* c4 = reinterpret_cast<const float4*>(xc);
    int tid = blockIdx.x * RTHREADS + threadIdx.x;
    float sg = 0.f, sm = 0.f;
    constexpr int STRIDE = RBLOCKS * RTHREADS;
#pragma unroll
    for (int it = 0; it < (DIM / 4) / STRIDE; ++it) {  // 4 iters
        int i = tid + it * STRIDE;
        float4 gv = g4[i];
        float4 pv = p4[i];
        float4 cv = c4[i];
        sg += gv.x * gv.x + gv.y * gv.y + gv.z * gv.z + gv.w * gv.w;
        float mx = cv.x - pv.x, my = cv.y - pv.y, mz = cv.z - pv.z, mw = cv.w - pv.w;
        sm += mx * mx + my * my + mz * mz + mw * mw;
    }
#pragma unroll
    for (int off = 32; off > 0; off >>= 1) {
        sg += __shfl_down(sg, off);
        sm += __shfl_down(sm, off);
    }
    __shared__ float wg[4], wm[4];
    int wave = threadIdx.x >> 6;
    if ((threadIdx.x & 63) == 0) {
        wg[wave] = sg;
        wm[wave] = sm;
    }
    __syncthreads();
    if (threadIdx.x == 0) {
        ws[WS_PART + 2 * blockIdx.x]     = wg[0] + wg[1] + wg[2] + wg[3];
        ws[WS_PART + 2 * blockIdx.x + 1] = wm[0] + wm[1] + wm[2] + wm[3];
    }
}

// ------- Kernel 2: redundant scalar finish + MFMA-chained direction network -------
__global__ __launch_bounds__(FTHREADS, 4) void k_fused(
    const float* __restrict__ grad, const float* __restrict__ xp, const float* __restrict__ xc,
    const float* __restrict__ loss_curr, const float* __restrict__ loss_prev,
    const float* __restrict__ Wl1, const float* __restrict__ Wl2, const float* __restrict__ Wl3,
    const float* __restrict__ Wl4, const float* __restrict__ Wl5,
    const float* __restrict__ ws, float* __restrict__ out) {
    __shared__ float sc[3];
    __shared__ float red[8];
    const int tid = threadIdx.x;

    // ---- phase A: every block finishes the norms in fixed order (identical result) ----
    {
        float fg = 0.f, fm = 0.f;
        for (int i = tid; i < RBLOCKS; i += FTHREADS) {
            fg += ws[WS_PART + 2 * i];
            fm += ws[WS_PART + 2 * i + 1];
        }
#pragma unroll
        for (int off = 32; off > 0; off >>= 1) {
            fg += __shfl_down(fg, off);
            fm += __shfl_down(fm, off);
        }
        int wv = tid >> 6;
        if ((tid & 63) == 0) {
            red[wv] = fg;
            red[4 + wv] = fm;
        }
        __syncthreads();
        if (tid == 0) {
            float g2 = red[0] + red[1] + red[2] + red[3];
            float m2 = red[4] + red[5] + red[6] + red[7];
            float g_norm = sqrtf(g2), m_norm = sqrtf(m2);
            float g_inv = (g_norm > EPSF) ? 1.f / g_norm : 1.f;
            float m_inv = (m_norm > EPSF) ? 1.f / m_norm : 1.f;
            float feats[4] = {log1pf(g_norm), log1pf(m_norm), log1pf(loss_curr[0]),
                              log1pf(loss_prev[0])};
            float h1[8], h2_[8], h3[8], h4[8];
#pragma unroll
            for (int o = 0; o < 8; ++o) {
                float acc = 0.f;
                for (int i = 0; i < 4; ++i) acc += Wl1[o * 4 + i] * feats[i];
                h1[o] = fmaxf(acc, 0.f);
            }
#pragma unroll
            for (int o = 0; o < 8; ++o) {
                float acc = 0.f;
                for (int i = 0; i < 8; ++i) acc += Wl2[o * 8 + i] * h1[i];
                h2_[o] = fmaxf(acc, 0.f);
            }
#pragma unroll
            for (int o = 0; o < 8; ++o) {
                float acc = 0.f;
                for (int i = 0; i < 8; ++i) acc += Wl3[o * 8 + i] * h2_[i];
                h3[o] = fmaxf(acc, 0.f);
            }
#pragma unroll
            for (int o = 0; o < 8; ++o) {
                float acc = 0.f;
                for (int i = 0; i < 8; ++i) acc += Wl4[o * 8 + i] * h3[i];
                h4[o] = acc;  // no relu
            }
            float step = 0.f;
            for (int i = 0; i < 8; ++i) step += Wl5[i] * h4[i];
            sc[0] = g_inv * SCALE;
            sc[1] = m_inv * SCALE;
            sc[2] = step * (1.f / SCALE);
        }
        __syncthreads();
    }
    const float gs = sc[0], ms = sc[1], step_eff = sc[2];

    // ---- per-lane weight fragments: lower K-half from ws, upper K-half = 0 ----
    const u32* wsu = (const u32*)ws;
    const int lane = tid & 63;
    const int n = lane & 15, g = lane >> 4;
#define LOADFRAG(NAME, OFS)                                                    \
    half8 NAME;                                                                \
    {                                                                          \
        u32x2 lo = ((const u32x2*)(wsu + (OFS)))[lane];                        \
        u32x4 fr = {lo[0], lo[1], 0u, 0u};                                     \
        NAME = __builtin_bit_cast(half8, fr);                                  \
    }
    LOADFRAG(w21f, WS_W21)
    LOADFRAG(w3f, WS_W3)
    LOADFRAG(w4f, WS_W4)
    LOADFRAG(w5f, WS_W5)
#undef LOADFRAG
    half8 w67f;
    {
        const float* w67p = ws + WS_W67;  // w67 replicated into all 16 A-rows
        u32x4 fr = {pack2u(w67p[4 * g], w67p[4 * g + 1]),
                    pack2u(w67p[4 * g + 2], w67p[4 * g + 3]), 0u, 0u};
        w67f = __builtin_bit_cast(half8, fr);
    }
    const f32x4 zf = {0.f, 0.f, 0.f, 0.f};

    int ebase = (blockIdx.x * (FTHREADS / 64) + (tid >> 6)) * 64 + lane;
    int e = ebase;
    float gvv = grad[e], pvv = xp[e], cvv = xc[e];
#pragma unroll
    for (int p = 0; p < PASSES; ++p) {
        int en = (p + 1 < PASSES) ? (e + TOTTH) : 0;  // prefetch next pass (clamped)
        float gvn = grad[en], pvn = xp[en], cvn = xc[en];

        float Gf = gvv * gs;
        float Mf = (cvv - pvv) * ms;
        float GMf = Gf * Mf;
        u32 pk0 = pack2u(Gf, Mf), pk1 = pack2u(GMf, 0.f);

        // --- level-batched: 4 independent tile chains, explicit ILP ---
        u32 b0[4], b1[4];
#pragma unroll
        for (int t = 0; t < 4; ++t) {
            int idx = (n + 16 * t) << 2;
            b0[t] = (u32)__builtin_amdgcn_ds_bpermute(idx, (int)pk0);
            b1[t] = (u32)__builtin_amdgcn_ds_bpermute(idx, (int)pk1);
        }
        f32x4 acc[4];
#pragma unroll
        for (int t = 0; t < 4; ++t) {
            u32x4 bb = {b0[t], b1[t], 0u, 0u};
            acc[t] = mfma32(w21f, __builtin_bit_cast(half8, bb), zf);
        }
#pragma unroll
        for (int t = 0; t < 4; ++t) acc[t] = mfma32(w3f, relucvt8(acc[t]), zf);
#pragma unroll
        for (int t = 0; t < 4; ++t) acc[t] = mfma32(w4f, relucvt8(acc[t]), zf);
#pragma unroll
        for (int t = 0; t < 4; ++t) acc[t] = mfma32(w5f, relucvt8(acc[t]), zf);
#pragma unroll
        for (int t = 0; t < 4; ++t) acc[t] = mfma32(w67f, relucvt8(acc[t]), zf);

        float dsel = (g == 0) ? acc[0][0] : (g == 1) ? acc[1][0] : (g == 2) ? acc[2][0]
                                                                            : acc[3][0];
        out[e] = fmaf(-step_eff, dsel, cvv);

        e = (p + 1 < PASSES) ? en : e;
        gvv = gvn;
        pvv = pvn;
        cvv = cvn;
    }
}

extern "C" void kernel_launch(void* const* d_in, const int* in_sizes, int n_in,
                              void* d_out, int out_size, void* d_ws, size_t ws_size,
                              hipStream_t stream) {
    const float* grad      = (const float*)d_in[0];
    const float* xp        = (const float*)d_in[1];
    const float* xc        = (const float*)d_in[2];
    const float* loss_curr = (const float*)d_in[3];
    const float* loss_prev = (const float*)d_in[4];
    const float* Wc1 = (const float*)d_in[5];
    const float* Wc2 = (const float*)d_in[6];
    const float* Wc3 = (const float*)d_in[7];
    const float* Wc4 = (const float*)d_in[8];
    const float* Wc5 = (const float*)d_in[9];
    const float* Wc6 = (const float*)d_in[10];
    const float* Wc7 = (const float*)d_in[11];
    const float* Wl1 = (const float*)d_in[12];
    const float* Wl2 = (const float*)d_in[13];
    const float* Wl3 = (const float*)d_in[14];
    const float* Wl4 = (const float*)d_in[15];
    const float* Wl5 = (const float*)d_in[16];

    float* ws  = (float*)d_ws;
    float* out = (float*)d_out;

    k_reduce<<<RBLOCKS, RTHREADS, 0, stream>>>(grad, xp, xc, Wc1, Wc2, Wc3, Wc4, Wc5, Wc6,
                                               Wc7, ws);
    k_fused<<<FBLOCKS, FTHREADS, 0, stream>>>(grad, xp, xc, loss_curr, loss_prev, Wl1, Wl2,
                                              Wl3, Wl4, Wl5, ws, out);
}